// Round 6
// baseline (25.050 us; speedup 1.0000x reference)
//
#include <hip/hip_runtime.h>

#define NN 1024
#define BB 16
#define NTY 3
#define PADF 32   // floats per accumulator slot = 128 B = 1 cacheline

// s_tbl[ti*3+tj] = (py, lpx, ry, lry):
//   phi  = 2^( py*d + lpx )   py = -p1*log2e        lpx = log2(p0) + p1*p2*log2e
//   rho² = 2^( ry*d + lry )   ry = -2*r1*log2e      lry = 2*(log2(r0) + r1*r2*log2e)
__global__ __launch_bounds__(256) void eam_fused(
    const int* __restrict__ types, const int* __restrict__ n_atoms,
    const float* __restrict__ distances,
    const float* __restrict__ phi_params, const float* __restrict__ rho_params,
    const float* __restrict__ emb_params,
    float* __restrict__ ws_acc, int* __restrict__ ws_cnt,
    float* __restrict__ out)
{
    __shared__ int4   s_types4[NN / 4];
    __shared__ float4 s_tbl[NTY * NTY];
    __shared__ float  s_rowe[8];

    const int tid = threadIdx.x;
    const int b  = blockIdx.y;
    const int bx = blockIdx.x;          // 0..127

    s_types4[tid] = ((const int4*)(types + b * NN))[tid];

    if (tid < NTY * NTY) {
        const int ti = tid / NTY, tj = tid % NTY;
        const int lo = min(ti, tj), hi = max(ti, tj);
        const int pt = lo * (2 * NTY - lo + 1) / 2 + (hi - lo);
        const float p0 = phi_params[pt * 3 + 0];
        const float p1 = phi_params[pt * 3 + 1];
        const float p2 = phi_params[pt * 3 + 2];
        const float r0 = rho_params[pt * 3 + 0];
        const float r1 = rho_params[pt * 3 + 1];
        const float r2 = rho_params[pt * 3 + 2];
        const float LOG2E = 1.44269504088896f;
        s_tbl[tid] = make_float4(
            -p1 * LOG2E, __log2f(p0) + p1 * p2 * LOG2E,
            -2.0f * r1 * LOG2E, 2.0f * (__log2f(r0) + r1 * r2 * LOG2E));
    }
    __syncthreads();

    const int lane = tid & 63;
    const int wave = tid >> 6;
    const int na = n_atoms[b];
    const bool p2 = na > 512;
    const bool p3 = na > 768;
    const int* s_types = (const int*)s_types4;

    const int iA = bx + wave * 256;     // strided rows: balanced tail
    const int iB = iA + 128;
    const bool vA = iA < na;
    const bool vB = iB < na;

    const float4 z4 = make_float4(0.f, 0.f, 0.f, 0.f);
    float4 a0 = z4, a1 = z4, a2 = z4, a3 = z4;
    float4 b0 = z4, b1 = z4, b2 = z4, b3 = z4;
    float dAii = 0.f, dBii = 0.f;
    int tiA = 0, tiB = 0;

    if (vA) {
        tiA = s_types[iA];
        const float4* rA = (const float4*)(distances + ((size_t)(b * NN + iA)) * NN);
        a0 = rA[lane];
        a1 = rA[64 + lane];
        if (p2) a2 = rA[128 + lane];
        if (p3) a3 = rA[192 + lane];
        dAii = ((const float*)rA)[iA];
    }
    if (vB) {
        tiB = s_types[iB];
        const float4* rB = (const float4*)(distances + ((size_t)(b * NN + iB)) * NN);
        b0 = rB[lane];
        b1 = rB[64 + lane];
        if (p2) b2 = rB[128 + lane];
        if (p3) b3 = rB[192 + lane];
        dBii = ((const float*)rB)[iB];
    }

    // hoist this wave's 2 rows' candidate params into registers
    const float4 cA0 = s_tbl[tiA * NTY + 0];
    const float4 cA1 = s_tbl[tiA * NTY + 1];
    const float4 cA2 = s_tbl[tiA * NTY + 2];
    const float4 cB0 = s_tbl[tiB * NTY + 0];
    const float4 cB1 = s_tbl[tiB * NTY + 1];
    const float4 cB2 = s_tbl[tiB * NTY + 2];

    float sphA = 0.f, srhA = 0.f, sphB = 0.f, srhB = 0.f;

#define SEL(C, F) (c2 ? (C##2).F : (c1 ? (C##1).F : (C##0).F))
#define EAM_EL(E, DA, DB, TT, MASKED, JB)                                     \
    {                                                                         \
        const int tj = (TT);                                                  \
        const bool c1 = tj >= 1, c2 = tj >= 2;                                \
        float phA = __builtin_amdgcn_exp2f(fmaf(SEL(cA,x),(DA),SEL(cA,y)));   \
        float rhA = __builtin_amdgcn_exp2f(fmaf(SEL(cA,z),(DA),SEL(cA,w)));   \
        float phB = __builtin_amdgcn_exp2f(fmaf(SEL(cB,x),(DB),SEL(cB,y)));   \
        float rhB = __builtin_amdgcn_exp2f(fmaf(SEL(cB,z),(DB),SEL(cB,w)));   \
        if (MASKED) {                                                         \
            const int j = (JB) + (E);                                         \
            if (j >= na) { phA = 0.f; rhA = 0.f; phB = 0.f; rhB = 0.f; }      \
        }                                                                     \
        sphA += phA; srhA += rhA; sphB += phB; srhB += rhB;                   \
    }
#define EAM_PASS(P, VA, VB, MASKED)                                           \
    {                                                                         \
        const int c4 = (P) * 64 + lane;                                       \
        const int4 tj4 = s_types4[c4];                                        \
        const int jb = c4 * 4;                                                \
        EAM_EL(0, (VA).x, (VB).x, tj4.x, MASKED, jb)                          \
        EAM_EL(1, (VA).y, (VB).y, tj4.y, MASKED, jb)                          \
        EAM_EL(2, (VA).z, (VB).z, tj4.z, MASKED, jb)                          \
        EAM_EL(3, (VA).w, (VB).w, tj4.w, MASKED, jb)                          \
    }
    EAM_PASS(0, a0, b0, false)
    EAM_PASS(1, a1, b1, false)
    if (p3) {
        EAM_PASS(2, a2, b2, false)
        EAM_PASS(3, a3, b3, true)
    } else if (p2) {
        EAM_PASS(2, a2, b2, true)
    }
#undef EAM_PASS
#undef EAM_EL
#undef SEL

#pragma unroll
    for (int o = 32; o > 0; o >>= 1) {
        sphA += __shfl_xor(sphA, o, 64);
        srhA += __shfl_xor(srhA, o, 64);
        sphB += __shfl_xor(sphB, o, 64);
        srhB += __shfl_xor(srhB, o, 64);
    }

    if (lane == 0) {
        float eA = 0.f, eB = 0.f;
        if (vA) {
            const float4 cd = (tiA == 0) ? cA0 : (tiA == 1) ? cA1 : cA2;
            const float phid = __builtin_amdgcn_exp2f(fmaf(cd.x, dAii, cd.y));
            const float rhid = __builtin_amdgcn_exp2f(fmaf(cd.z, dAii, cd.w));
            const float A   = emb_params[tiA * 2 + 0];
            const float off = emb_params[tiA * 2 + 1];
            eA = (sphA - phid) + (-A * sqrtf(fmaxf(srhA - rhid, 1e-30f)) + off);
        }
        if (vB) {
            const float4 cd = (tiB == 0) ? cB0 : (tiB == 1) ? cB1 : cB2;
            const float phid = __builtin_amdgcn_exp2f(fmaf(cd.x, dBii, cd.y));
            const float rhid = __builtin_amdgcn_exp2f(fmaf(cd.z, dBii, cd.w));
            const float A   = emb_params[tiB * 2 + 0];
            const float off = emb_params[tiB * 2 + 1];
            eB = (sphB - phid) + (-A * sqrtf(fmaxf(srhB - rhid, 1e-30f)) + off);
        }
        s_rowe[wave * 2 + 0] = eA;
        s_rowe[wave * 2 + 1] = eB;
    }
    __syncthreads();

    if (tid == 0) {
        float s = 0.f;
#pragma unroll
        for (int k = 0; k < 8; ++k) s += s_rowe[k];

        // one padded line per batch: 128 RMWs/line, 16 lines in parallel
        const float oldv = atomicAdd(&ws_acc[b * PADF], s);
        // consume return value -> compiler emits s_waitcnt vmcnt(0) here,
        // guaranteeing the value-add completed at L2 before the ticket-add
        asm volatile("" :: "v"(oldv));
        const int ticket = atomicAdd(&ws_cnt[b * PADF], 1);
        if (ticket == 127) {
            // all 128 value-adds for batch b are L2-visible; RMW-read the total
            const float total = atomicAdd(&ws_acc[b * PADF], 0.0f);
            out[b] = total / (float)na;
        }
    }
}

extern "C" void kernel_launch(void* const* d_in, const int* in_sizes, int n_in,
                              void* d_out, int out_size, void* d_ws, size_t ws_size,
                              hipStream_t stream) {
    const int*   types      = (const int*)d_in[0];
    const int*   n_atoms    = (const int*)d_in[1];
    const float* distances  = (const float*)d_in[2];
    // d_in[3] = pair_types: recomputed on the fly, not read
    const float* phi_params = (const float*)d_in[4];
    const float* rho_params = (const float*)d_in[5];
    const float* emb_params = (const float*)d_in[6];

    float* ws_acc = (float*)d_ws;                          // 16 lines
    int*   ws_cnt = (int*)((char*)d_ws + BB * PADF * 4);   // 16 lines

    // zero accumulators + tickets (8 KB) each call — graph-capturable node
    hipMemsetAsync(d_ws, 0, 2 * BB * PADF * 4, stream);

    eam_fused<<<dim3(128, BB), 256, 0, stream>>>(
        types, n_atoms, distances, phi_params, rho_params, emb_params,
        ws_acc, ws_cnt, (float*)d_out);
}

// Round 7
// 20.072 us; speedup vs baseline: 1.2480x; 1.2480x over previous
//
#include <hip/hip_runtime.h>

#define NN 1024
#define BB 16
#define NTY 3

typedef float v2f __attribute__((ext_vector_type(2)));

__device__ __forceinline__ v2f pk_fma(v2f a, v2f b, v2f c) {
    v2f d;
    asm("v_pk_fma_f32 %0, %1, %2, %3" : "=v"(d) : "v"(a), "v"(b), "v"(c));
    return d;
}

// s_tbl[ti*3+tj] = (py, lpx, ry, lry):
//   phi  = 2^( py*d + lpx )   py = -p1*log2e        lpx = log2(p0) + p1*p2*log2e
//   rho² = 2^( ry*d + lry )   ry = -2*r1*log2e      lry = 2*(log2(r0) + r1*r2*log2e)
__global__ __launch_bounds__(256) void eam_rows(
    const int* __restrict__ types, const int* __restrict__ n_atoms,
    const float* __restrict__ distances,
    const float* __restrict__ phi_params, const float* __restrict__ rho_params,
    const float* __restrict__ emb_params, float* __restrict__ blk_part)
{
    __shared__ int4   s_types4[NN / 4];
    __shared__ float4 s_tbl[NTY * NTY];
    __shared__ float  s_rowe[8];

    const int tid = threadIdx.x;
    const int b  = blockIdx.y;
    const int bx = blockIdx.x;          // 0..127

    s_types4[tid] = ((const int4*)(types + b * NN))[tid];

    if (tid < NTY * NTY) {
        const int ti = tid / NTY, tj = tid % NTY;
        const int lo = min(ti, tj), hi = max(ti, tj);
        const int pt = lo * (2 * NTY - lo + 1) / 2 + (hi - lo);
        const float p0 = phi_params[pt * 3 + 0];
        const float p1 = phi_params[pt * 3 + 1];
        const float p2 = phi_params[pt * 3 + 2];
        const float r0 = rho_params[pt * 3 + 0];
        const float r1 = rho_params[pt * 3 + 1];
        const float r2 = rho_params[pt * 3 + 2];
        const float LOG2E = 1.44269504088896f;
        s_tbl[tid] = make_float4(
            -p1 * LOG2E, __log2f(p0) + p1 * p2 * LOG2E,
            -2.0f * r1 * LOG2E, 2.0f * (__log2f(r0) + r1 * r2 * LOG2E));
    }
    __syncthreads();

    const int lane = tid & 63;
    const int wave = tid >> 6;
    const int na = n_atoms[b];
    const bool p2 = na > 512;
    const bool p3 = na > 768;
    const int* s_types = (const int*)s_types4;

    const int iA = bx + wave * 256;     // strided rows: balanced tail
    const int iB = iA + 128;
    const bool vA = iA < na;
    const bool vB = iB < na;

    const float4 z4 = make_float4(0.f, 0.f, 0.f, 0.f);
    float4 a0 = z4, a1 = z4, a2 = z4, a3 = z4;
    float4 b0 = z4, b1 = z4, b2 = z4, b3 = z4;
    float dAii = 0.f, dBii = 0.f;
    int tiA = 0, tiB = 0;

    if (vA) {
        tiA = s_types[iA];
        const float4* rA = (const float4*)(distances + ((size_t)(b * NN + iA)) * NN);
        a0 = rA[lane];
        a1 = rA[64 + lane];
        if (p2) a2 = rA[128 + lane];
        if (p3) a3 = rA[192 + lane];
        dAii = ((const float*)rA)[iA];
    }
    if (vB) {
        tiB = s_types[iB];
        const float4* rB = (const float4*)(distances + ((size_t)(b * NN + iB)) * NN);
        b0 = rB[lane];
        b1 = rB[64 + lane];
        if (p2) b2 = rB[128 + lane];
        if (p3) b3 = rB[192 + lane];
        dBii = ((const float*)rB)[iB];
    }

    // hoist params as packed pairs: PY=(py,ry), PL=(lpx,lry) per tj candidate
    const float4 tA0 = s_tbl[tiA * NTY + 0];
    const float4 tA1 = s_tbl[tiA * NTY + 1];
    const float4 tA2 = s_tbl[tiA * NTY + 2];
    const float4 tB0 = s_tbl[tiB * NTY + 0];
    const float4 tB1 = s_tbl[tiB * NTY + 1];
    const float4 tB2 = s_tbl[tiB * NTY + 2];
    const v2f pyA0 = {tA0.x, tA0.z}, plA0 = {tA0.y, tA0.w};
    const v2f pyA1 = {tA1.x, tA1.z}, plA1 = {tA1.y, tA1.w};
    const v2f pyA2 = {tA2.x, tA2.z}, plA2 = {tA2.y, tA2.w};
    const v2f pyB0 = {tB0.x, tB0.z}, plB0 = {tB0.y, tB0.w};
    const v2f pyB1 = {tB1.x, tB1.z}, plB1 = {tB1.y, tB1.w};
    const v2f pyB2 = {tB2.x, tB2.z}, plB2 = {tB2.y, tB2.w};

    v2f accA = {0.f, 0.f};   // (sum_phi, sum_rho²) row A
    v2f accB = {0.f, 0.f};

#define EAM_EL(E, DD, TT, MASKED, JB)                                         \
    {                                                                         \
        const int tj = (TT);                                                  \
        const bool c1 = tj >= 1, c2 = tj >= 2;                                \
        const float dv = (DD);                                                \
        const v2f dd = {dv, dv};                                              \
        const v2f pyA = c2 ? pyA2 : (c1 ? pyA1 : pyA0);                       \
        const v2f plA = c2 ? plA2 : (c1 ? plA1 : plA0);                       \
        const v2f gA = pk_fma(pyA, dd, plA);                                  \
        const v2f pyB = c2 ? pyB2 : (c1 ? pyB1 : pyB0);                       \
        const v2f plB = c2 ? plB2 : (c1 ? plB1 : plB0);                       \
        const v2f gB = pk_fma(pyB, dd, plB);                                  \
        v2f eA = {__builtin_amdgcn_exp2f(gA.x), __builtin_amdgcn_exp2f(gA.y)};\
        v2f eB = {__builtin_amdgcn_exp2f(gB.x), __builtin_amdgcn_exp2f(gB.y)};\
        if (MASKED) {                                                         \
            const int j = (JB) + (E);                                         \
            if (j >= na) { eA = (v2f){0.f, 0.f}; eB = (v2f){0.f, 0.f}; }      \
        }                                                                     \
        accA += eA;                                                           \
        accB += eB;                                                           \
    }
#define EAM_PASS(P, VA, VB, MASKED)                                           \
    {                                                                         \
        const int c4 = (P) * 64 + lane;                                       \
        const int4 tj4 = s_types4[c4];                                        \
        const int jb = c4 * 4;                                                \
        EAM_EL(0, (VA).x, tj4.x, MASKED, jb)                                  \
        EAM_EL(1, (VA).y, tj4.y, MASKED, jb)                                  \
        EAM_EL(2, (VA).z, tj4.z, MASKED, jb)                                  \
        EAM_EL(3, (VA).w, tj4.w, MASKED, jb)                                  \
    }
    // note: EAM_EL uses VA's component for row A and VB's for row B
#undef EAM_PASS
#define EAM_PASS(P, VA, VB, MASKED)                                           \
    {                                                                         \
        const int c4 = (P) * 64 + lane;                                       \
        const int4 tj4 = s_types4[c4];                                        \
        const int jb = c4 * 4;                                                \
        EAM_EL2(0, (VA).x, (VB).x, tj4.x, MASKED, jb)                         \
        EAM_EL2(1, (VA).y, (VB).y, tj4.y, MASKED, jb)                         \
        EAM_EL2(2, (VA).z, (VB).z, tj4.z, MASKED, jb)                         \
        EAM_EL2(3, (VA).w, (VB).w, tj4.w, MASKED, jb)                         \
    }
#define EAM_EL2(E, DA, DB, TT, MASKED, JB)                                    \
    {                                                                         \
        const int tj = (TT);                                                  \
        const bool c1 = tj >= 1, c2 = tj >= 2;                                \
        const v2f ddA = {(DA), (DA)};                                         \
        const v2f ddB = {(DB), (DB)};                                         \
        const v2f pyA = c2 ? pyA2 : (c1 ? pyA1 : pyA0);                       \
        const v2f plA = c2 ? plA2 : (c1 ? plA1 : plA0);                       \
        const v2f gA = pk_fma(pyA, ddA, plA);                                 \
        const v2f pyB = c2 ? pyB2 : (c1 ? pyB1 : pyB0);                       \
        const v2f plB = c2 ? plB2 : (c1 ? plB1 : plB0);                       \
        const v2f gB = pk_fma(pyB, ddB, plB);                                 \
        v2f eA = {__builtin_amdgcn_exp2f(gA.x), __builtin_amdgcn_exp2f(gA.y)};\
        v2f eB = {__builtin_amdgcn_exp2f(gB.x), __builtin_amdgcn_exp2f(gB.y)};\
        if (MASKED) {                                                         \
            const int j = (JB) + (E);                                         \
            if (j >= na) { eA = (v2f){0.f, 0.f}; eB = (v2f){0.f, 0.f}; }      \
        }                                                                     \
        accA += eA;                                                           \
        accB += eB;                                                           \
    }
    EAM_PASS(0, a0, b0, false)
    EAM_PASS(1, a1, b1, false)
    if (p3) {
        EAM_PASS(2, a2, b2, false)
        EAM_PASS(3, a3, b3, true)
    } else if (p2) {
        EAM_PASS(2, a2, b2, true)
    }
#undef EAM_PASS
#undef EAM_EL2
#undef EAM_EL

    float sphA = accA.x, srhA = accA.y, sphB = accB.x, srhB = accB.y;
#pragma unroll
    for (int o = 32; o > 0; o >>= 1) {
        sphA += __shfl_xor(sphA, o, 64);
        srhA += __shfl_xor(srhA, o, 64);
        sphB += __shfl_xor(sphB, o, 64);
        srhB += __shfl_xor(srhB, o, 64);
    }

    if (lane == 0) {
        float eA = 0.f, eB = 0.f;
        if (vA) {
            const v2f pyd = (tiA == 0) ? pyA0 : (tiA == 1) ? pyA1 : pyA2;
            const v2f pld = (tiA == 0) ? plA0 : (tiA == 1) ? plA1 : plA2;
            const float phid = __builtin_amdgcn_exp2f(fmaf(pyd.x, dAii, pld.x));
            const float rhid = __builtin_amdgcn_exp2f(fmaf(pyd.y, dAii, pld.y));
            const float A   = emb_params[tiA * 2 + 0];
            const float off = emb_params[tiA * 2 + 1];
            eA = (sphA - phid) + (-A * sqrtf(fmaxf(srhA - rhid, 1e-30f)) + off);
        }
        if (vB) {
            const v2f pyd = (tiB == 0) ? pyB0 : (tiB == 1) ? pyB1 : pyB2;
            const v2f pld = (tiB == 0) ? plB0 : (tiB == 1) ? plB1 : plB2;
            const float phid = __builtin_amdgcn_exp2f(fmaf(pyd.x, dBii, pld.x));
            const float rhid = __builtin_amdgcn_exp2f(fmaf(pyd.y, dBii, pld.y));
            const float A   = emb_params[tiB * 2 + 0];
            const float off = emb_params[tiB * 2 + 1];
            eB = (sphB - phid) + (-A * sqrtf(fmaxf(srhB - rhid, 1e-30f)) + off);
        }
        s_rowe[wave * 2 + 0] = eA;
        s_rowe[wave * 2 + 1] = eB;
    }
    __syncthreads();

    if (tid == 0) {
        float s = 0.f;
#pragma unroll
        for (int k = 0; k < 8; ++k) s += s_rowe[k];
        blk_part[b * 128 + bx] = s;     // plain store — no atomics, no fences
    }
}

__global__ __launch_bounds__(64) void eam_reduce(
    const float* __restrict__ blk_part, const int* __restrict__ n_atoms,
    float* __restrict__ out)
{
    const int b = blockIdx.x;
    const int lane = threadIdx.x;
    float s = blk_part[b * 128 + lane] + blk_part[b * 128 + 64 + lane];
#pragma unroll
    for (int o = 32; o > 0; o >>= 1) s += __shfl_xor(s, o, 64);
    if (lane == 0) out[b] = s / (float)n_atoms[b];
}

extern "C" void kernel_launch(void* const* d_in, const int* in_sizes, int n_in,
                              void* d_out, int out_size, void* d_ws, size_t ws_size,
                              hipStream_t stream) {
    const int*   types      = (const int*)d_in[0];
    const int*   n_atoms    = (const int*)d_in[1];
    const float* distances  = (const float*)d_in[2];
    // d_in[3] = pair_types: recomputed on the fly, not read
    const float* phi_params = (const float*)d_in[4];
    const float* rho_params = (const float*)d_in[5];
    const float* emb_params = (const float*)d_in[6];

    float* blk_part = (float*)d_ws;   // 16*128 floats = 8 KB

    eam_rows<<<dim3(128, BB), 256, 0, stream>>>(
        types, n_atoms, distances, phi_params, rho_params, emb_params, blk_part);
    eam_reduce<<<BB, 64, 0, stream>>>(blk_part, n_atoms, (float*)d_out);
}